// Round 5
// baseline (611.907 us; speedup 1.0000x reference)
//
#include <hip/hip_runtime.h>

#define SCALEF 0.17677669529663687f                 // 32^-0.5
#define LOG2E 1.4426950408889634f
#define SCALE2 (0.17677669529663687f * 1.4426950408889634f)
#define SWZ(r) ((((r) & 3) << 6) | (((r) & 12) << 2))   // bits >=4 only: b128-safe

typedef __attribute__((ext_vector_type(8))) short short8;   // 8 bf16
typedef __attribute__((ext_vector_type(4))) float f32x4;
typedef __attribute__((ext_vector_type(4))) unsigned int u32x4;

__device__ __forceinline__ unsigned short f2bf(float f) {
  unsigned u = __builtin_bit_cast(unsigned, f);
  u = (u + 0x7FFFu + ((u >> 16) & 1u)) >> 16;
  return (unsigned short)u;
}
__device__ __forceinline__ short8 ld8(const unsigned short* p) { return *(const short8*)p; }
__device__ __forceinline__ unsigned cvtpk(float a, float b) {
  unsigned d;
  asm("v_cvt_pk_bf16_f32 %0, %1, %2" : "=v"(d) : "v"(a), "v"(b));
  return d;
}

// Build an MFMA A/B-frag (lane lo -> row, k = hi*8+e) from two 16x16 C-tiles
// whose ROWS are the k-dimension (t0: k 0..15, t1: k 16..31).
__device__ __forceinline__ short8 xform(f32x4 t0, f32x4 t1, int lo, int hi) {
  unsigned A01 = cvtpk(t0[0], t0[1]), A23 = cvtpk(t0[2], t0[3]);
  unsigned B01 = cvtpk(t1[0], t1[1]), B23 = cvtpk(t1[2], t1[3]);
  int s0 = ((2 * hi) & 3) * 16 + lo;
  int s1 = ((2 * hi + 1) & 3) * 16 + lo;
  bool up = hi >= 2;
  unsigned a, b;
  a = __shfl(A01, s0); b = __shfl(B01, s0); unsigned dw0 = up ? b : a;
  a = __shfl(A23, s0); b = __shfl(B23, s0); unsigned dw1 = up ? b : a;
  a = __shfl(A01, s1); b = __shfl(B01, s1); unsigned dw2 = up ? b : a;
  a = __shfl(A23, s1); b = __shfl(B23, s1); unsigned dw3 = up ? b : a;
  u32x4 v = {dw0, dw1, dw2, dw3};
  return __builtin_bit_cast(short8, v);
}

// gelu(x) ~= x * sigmoid(2*0.79788456*(x+0.044715x^3)); in exp2 domain.
__device__ __forceinline__ float gelu_f(float x) {
  float x2 = x * x;
  float t = __builtin_fmaf(-0.10294824f, x2, -2.30220823f);  // -2*log2e*0.7978846*(1+0.044715x^2)
  float e = __builtin_amdgcn_exp2f(t * x);
  return x * __builtin_amdgcn_rcpf(e + 1.0f);
}

// ---------------------------------------------------------------- K0a: weights fp32 -> bf16
__global__ __launch_bounds__(256) void k_cvt(const float* qkvw, const float* projw,
                                             const float* fc1w, const float* fc2w,
                                             unsigned short* wbuf) {
  int i = blockIdx.x * 256 + threadIdx.x;
  float v;
  if (i < 49152) v = qkvw[i];
  else if (i < 65536) v = projw[i - 49152];
  else if (i < 131072) v = fc1w[i - 65536];
  else v = fc2w[i - 131072];
  wbuf[i] = f2bf(v);
}

// ---------------------------------------------------------------- K0b: bias+mask table, TRANSPOSED [w][h][j][i], pre-scaled by log2e
__device__ __forceinline__ int regio(int r) { return r < 49 ? 0 : (r < 53 ? 1 : 2); }

__global__ __launch_bounds__(256) void k_addtab(const float* rpb, float* at) {
  int idx = blockIdx.x * 256 + threadIdx.x;      // 64*4*49*49 = 614656 threads
  int i = idx % 49;                               // query token
  int tmp = idx / 49;
  int j = tmp % 49; tmp /= 49;                    // key token
  int h = tmp & 3;
  int w = tmp >> 2;
  int ih = i / 7, iw = i % 7, jh = j / 7, jw = j % 7;
  int rpi = (ih - jh + 6) * 13 + (iw - jw + 6);
  float bias = rpb[rpi * 4 + h];
  int wr = w >> 3, wc = w & 7;
  int idi = regio(wr * 7 + ih) * 3 + regio(wc * 7 + iw);
  int idj = regio(wr * 7 + jh) * 3 + regio(wc * 7 + jw);
  at[idx] = (bias + ((idi != idj) ? -100.0f : 0.0f)) * LOG2E;
}

// ---------------------------------------------------------------- K1: fused LN1+QKV+attn+proj+residual
// 1 block/window, 1 wave/head. LDS = 12.25 KB (X region only; K,V,P live in registers).
__global__ __launch_bounds__(256, 4) void k_attn(const float* __restrict__ x,
                                                 const float* __restrict__ g1,
                                                 const float* __restrict__ b1,
                                                 const unsigned short* __restrict__ wq,
                                                 const float* __restrict__ qb,
                                                 const unsigned short* __restrict__ wp,
                                                 const float* __restrict__ pb,
                                                 const float* __restrict__ addtab,
                                                 float* __restrict__ y) {
  __shared__ __align__(16) char L[12544];   // 49 rows x 256B, swizzled
  const int tid = threadIdx.x;
  const int wv = tid >> 6, l = tid & 63, lo = l & 15, hi = l >> 4;
  const int lh = l & 31, half = l >> 5;
  const int g = blockIdx.x, bimg = g >> 6, w_in = g & 63;
  const int wr = w_in >> 3, wc = w_in & 7;
  const int h = wv;
  const f32x4 fz = {0.f, 0.f, 0.f, 0.f};

  // ---- Phase 0: LN1 + roll(-3,-3) gather -> X (bf16, swizzled). 2 rows/iter (half-wave float4).
  #pragma unroll 1
  for (int ii = 0; ii < 7; ii++) {
    int r = ii * 8 + wv * 2 + half;
    if (r < 49) {
      int ihh = r / 7, iww = r - ihh * 7;
      int oh = wr * 7 + ihh + 3; if (oh >= 56) oh -= 56;
      int ow = wc * 7 + iww + 3; if (ow >= 56) ow -= 56;
      const float* src = x + ((size_t)bimg * 3136 + oh * 56 + ow) * 128 + lh * 4;
      float4 v = *(const float4*)src;
      float s = v.x + v.y + v.z + v.w;
      s += __shfl_xor(s, 1); s += __shfl_xor(s, 2); s += __shfl_xor(s, 4);
      s += __shfl_xor(s, 8); s += __shfl_xor(s, 16);
      float mu = s * (1.0f / 128.0f);
      float d0 = v.x - mu, d1 = v.y - mu, d2 = v.z - mu, d3 = v.w - mu;
      float q = d0 * d0 + d1 * d1 + d2 * d2 + d3 * d3;
      q += __shfl_xor(q, 1); q += __shfl_xor(q, 2); q += __shfl_xor(q, 4);
      q += __shfl_xor(q, 8); q += __shfl_xor(q, 16);
      float rs = rsqrtf(q * (1.0f / 128.0f) + 1e-5f);
      float4 gg = *(const float4*)(g1 + lh * 4);
      float4 bb = *(const float4*)(b1 + lh * 4);
      uint2 pk;
      pk.x = cvtpk(d0 * rs * gg.x + bb.x, d1 * rs * gg.y + bb.y);
      pk.y = cvtpk(d2 * rs * gg.z + bb.z, d3 * rs * gg.w + bb.w);
      *(uint2*)(L + r * 256 + ((lh * 8) ^ SWZ(r))) = pk;
    }
  }
  __syncthreads();

  // ---- Phase 1: Q^T and K^T GEMMs (merged, share X-fragment reads) -> in-reg frags
  short8 qbf[4], kaf[4];
  {
    f32x4 cq[2][4], ck[2][4];
    #pragma unroll
    for (int a = 0; a < 2; a++)
      #pragma unroll
      for (int b = 0; b < 4; b++) { cq[a][b] = fz; ck[a][b] = fz; }
    #pragma unroll
    for (int ks = 0; ks < 4; ks++) {
      short8 wq0 = ld8(wq + (size_t)(h * 32 + lo) * 128 + ks * 32 + hi * 8);
      short8 wq1 = ld8(wq + (size_t)(h * 32 + 16 + lo) * 128 + ks * 32 + hi * 8);
      short8 wk0 = ld8(wq + (size_t)(128 + h * 32 + lo) * 128 + ks * 32 + hi * 8);
      short8 wk1 = ld8(wq + (size_t)(128 + h * 32 + 16 + lo) * 128 + ks * 32 + hi * 8);
      #pragma unroll
      for (int nt = 0; nt < 4; nt++) {
        int row = nt * 16 + lo; if (row > 48) row = 48;
        short8 xbv = *(const short8*)(L + row * 256 + ((ks * 64 + hi * 16) ^ SWZ(row)));
        cq[0][nt] = __builtin_amdgcn_mfma_f32_16x16x32_bf16(wq0, xbv, cq[0][nt], 0, 0, 0);
        cq[1][nt] = __builtin_amdgcn_mfma_f32_16x16x32_bf16(wq1, xbv, cq[1][nt], 0, 0, 0);
        ck[0][nt] = __builtin_amdgcn_mfma_f32_16x16x32_bf16(wk0, xbv, ck[0][nt], 0, 0, 0);
        ck[1][nt] = __builtin_amdgcn_mfma_f32_16x16x32_bf16(wk1, xbv, ck[1][nt], 0, 0, 0);
      }
    }
    float4 qb0 = *(const float4*)(qb + h * 32 + 4 * hi);
    float4 qb1 = *(const float4*)(qb + h * 32 + 16 + 4 * hi);
    float4 kb0 = *(const float4*)(qb + 128 + h * 32 + 4 * hi);
    float4 kb1 = *(const float4*)(qb + 128 + h * 32 + 16 + 4 * hi);
    #pragma unroll
    for (int nt = 0; nt < 4; nt++) {
      f32x4 t0 = cq[0][nt], t1 = cq[1][nt];
      t0[0] += qb0.x; t0[1] += qb0.y; t0[2] += qb0.z; t0[3] += qb0.w;
      t1[0] += qb1.x; t1[1] += qb1.y; t1[2] += qb1.z; t1[3] += qb1.w;
      qbf[nt] = xform(t0, t1, lo, hi);
      t0 = ck[0][nt]; t1 = ck[1][nt];
      t0[0] += kb0.x; t0[1] += kb0.y; t0[2] += kb0.z; t0[3] += kb0.w;
      t1[0] += kb1.x; t1[1] += kb1.y; t1[2] += kb1.z; t1[3] += kb1.w;
      kaf[nt] = xform(t0, t1, lo, hi);
    }
  }

  // ---- Phase 2: V GEMM (untransposed), eager pair-xform -> in-reg B-frags vf[dtile][ks]
  short8 vf[2][2];
  {
    #pragma unroll
    for (int nt = 0; nt < 2; nt++) {
      float vb = qb[256 + h * 32 + nt * 16 + lo];
      #pragma unroll
      for (int p = 0; p < 2; p++) {
        f32x4 c0 = fz, c1 = fz;
        #pragma unroll
        for (int ks = 0; ks < 4; ks++) {
          short8 wb = ld8(wq + (size_t)(256 + h * 32 + nt * 16 + lo) * 128 + ks * 32 + hi * 8);
          int r0 = p * 32 + lo; if (r0 > 48) r0 = 48;
          int r1 = p * 32 + 16 + lo; if (r1 > 48) r1 = 48;
          short8 xa0 = *(const short8*)(L + r0 * 256 + ((ks * 64 + hi * 16) ^ SWZ(r0)));
          short8 xa1 = *(const short8*)(L + r1 * 256 + ((ks * 64 + hi * 16) ^ SWZ(r1)));
          c0 = __builtin_amdgcn_mfma_f32_16x16x32_bf16(xa0, wb, c0, 0, 0, 0);
          c1 = __builtin_amdgcn_mfma_f32_16x16x32_bf16(xa1, wb, c1, 0, 0, 0);
        }
        c0[0] += vb; c0[1] += vb; c0[2] += vb; c0[3] += vb;
        c1[0] += vb; c1[1] += vb; c1[2] += vb; c1[3] += vb;
        vf[nt][p] = xform(c0, c1, lo, hi);
      }
    }
  }

  // ---- Phase 3: S^T = K @ Q^T (C: row=j key token, col=i query token)
  f32x4 st[4][4];
  #pragma unroll
  for (int jt = 0; jt < 4; jt++)
    #pragma unroll
    for (int it = 0; it < 4; it++)
      st[jt][it] = __builtin_amdgcn_mfma_f32_16x16x32_bf16(kaf[jt], qbf[it], fz, 0, 0, 0);

  // ---- softmax over j (exp2 domain; addtab pre-scaled by log2e)
  const float* at = addtab + ((size_t)w_in * 4 + h) * 2401;
  #pragma unroll
  for (int it = 0; it < 4; it++) {
    int i = it * 16 + lo;
    int ic = i > 48 ? 48 : i;
    float vv[4][4];
    #pragma unroll
    for (int jt = 0; jt < 4; jt++) {
      #pragma unroll
      for (int r = 0; r < 4; r++) {
        int jj = jt * 16 + 4 * hi + r;
        int jc = jj > 48 ? 48 : jj;
        float sv = st[jt][it][r] * SCALE2 + at[jc * 49 + ic];
        vv[jt][r] = (jj < 49) ? sv : -1e30f;
      }
    }
    float mx = -1e30f;
    #pragma unroll
    for (int jt = 0; jt < 4; jt++)
      mx = fmaxf(mx, fmaxf(fmaxf(vv[jt][0], vv[jt][1]), fmaxf(vv[jt][2], vv[jt][3])));
    mx = fmaxf(mx, __shfl_xor(mx, 16));
    mx = fmaxf(mx, __shfl_xor(mx, 32));
    float sum = 0.0f;
    #pragma unroll
    for (int jt = 0; jt < 4; jt++)
      #pragma unroll
      for (int r = 0; r < 4; r++) {
        vv[jt][r] = __builtin_amdgcn_exp2f(vv[jt][r] - mx);
        sum += vv[jt][r];
      }
    sum += __shfl_xor(sum, 16);
    sum += __shfl_xor(sum, 32);
    float rinv = 1.0f / sum;
    #pragma unroll
    for (int jt = 0; jt < 4; jt++)
      #pragma unroll
      for (int r = 0; r < 4; r++)
        st[jt][it][r] = vv[jt][r] * rinv;
  }

  // ---- Phase 4: PV (P frags built in-register from st tiles)
  f32x4 o[4][2] = {};
  #pragma unroll
  for (int it = 0; it < 4; it++) {
    #pragma unroll
    for (int ks = 0; ks < 2; ks++) {
      short8 pf = xform(st[2 * ks][it], st[2 * ks + 1][it], lo, hi);
      #pragma unroll
      for (int td = 0; td < 2; td++)
        o[it][td] = __builtin_amdgcn_mfma_f32_16x16x32_bf16(pf, vf[td][ks], o[it][td], 0, 0, 0);
    }
  }
  __syncthreads();   // all X reads done block-wide; safe to overwrite with attnout

  // ---- stage attnout into X region [token][c], swizzled
  #pragma unroll
  for (int it = 0; it < 4; it++)
    #pragma unroll
    for (int td = 0; td < 2; td++)
      #pragma unroll
      for (int r = 0; r < 4; r++) {
        int i = it * 16 + 4 * hi + r;
        if (i < 49) {
          int c = h * 32 + td * 16 + lo;
          *(unsigned short*)(L + i * 256 + ((2 * c) ^ SWZ(i))) = f2bf(o[it][td][r]);
        }
      }
  __syncthreads();

  // ---- Phase 5: proj + window-reverse + roll(+3) + residual; wave wv -> cols [wv*32, +32)
  f32x4 pacc[4][2];
  #pragma unroll
  for (int a = 0; a < 4; a++) { pacc[a][0] = fz; pacc[a][1] = fz; }
  #pragma unroll
  for (int ks = 0; ks < 4; ks++) {
    short8 wb0 = ld8(wp + (size_t)(wv * 32 + lo) * 128 + ks * 32 + hi * 8);
    short8 wb1 = ld8(wp + (size_t)(wv * 32 + 16 + lo) * 128 + ks * 32 + hi * 8);
    #pragma unroll
    for (int mt = 0; mt < 4; mt++) {
      int tok = mt * 16 + lo; if (tok > 48) tok = 48;
      short8 a = *(const short8*)(L + tok * 256 + ((ks * 64 + hi * 16) ^ SWZ(tok)));
      pacc[mt][0] = __builtin_amdgcn_mfma_f32_16x16x32_bf16(a, wb0, pacc[mt][0], 0, 0, 0);
      pacc[mt][1] = __builtin_amdgcn_mfma_f32_16x16x32_bf16(a, wb1, pacc[mt][1], 0, 0, 0);
    }
  }
  float pb0 = pb[wv * 32 + lo], pb1 = pb[wv * 32 + 16 + lo];
  #pragma unroll
  for (int mt = 0; mt < 4; mt++) {
    #pragma unroll
    for (int r = 0; r < 4; r++) {
      int tok = mt * 16 + 4 * hi + r;
      if (tok < 49) {
        int ihh = tok / 7, iww = tok - ihh * 7;
        int oh = wr * 7 + ihh + 3; if (oh >= 56) oh -= 56;
        int ow = wc * 7 + iww + 3; if (ow >= 56) ow -= 56;
        size_t yrow = (size_t)bimg * 3136 + oh * 56 + ow;
        const float* xr = x + yrow * 128;
        float* yr = y + yrow * 128;
        int c0 = wv * 32 + lo, c1 = wv * 32 + 16 + lo;
        yr[c0] = pacc[mt][0][r] + pb0 + xr[c0];
        yr[c1] = pacc[mt][1][r] + pb1 + xr[c1];
      }
    }
  }
}

// ---------------------------------------------------------------- K2: fused LN2+fc1+GELU+fc2+residual, quarter-H pipeline
// 512 threads (8 waves), 64 rows/block, LDS 32 KB, target VGPR<=64 -> up to 4 blocks/CU.
__global__ __launch_bounds__(512, 8) void k_mlp(float* __restrict__ y,
                                                const float* __restrict__ g2, const float* __restrict__ b2,
                                                const unsigned short* __restrict__ w1, const float* __restrict__ bias1,
                                                const unsigned short* __restrict__ w2, const float* __restrict__ bias2) {
  __shared__ __align__(16) char Xl[16384];   // 64 x 256B, swizzled
  __shared__ __align__(16) char Hq[16384];   // 64 x 256B (one 128-col quarter of H), swizzled
  const int m0 = blockIdx.x * 64;
  const int tid = threadIdx.x;
  const int wv = tid >> 6, l = tid & 63, lo = l & 15, hi = l >> 4;
  const int lh = l & 31, half = l >> 5;
  const f32x4 fz = {0.f, 0.f, 0.f, 0.f};

  // --- LN2: 4 iters x 16 rows (8 waves x 2 rows, half-wave float4)
  #pragma unroll 1
  for (int it = 0; it < 4; it++) {
    int rloc = it * 16 + wv * 2 + half;
    const float* src = y + (size_t)(m0 + rloc) * 128 + lh * 4;
    float4 v = *(const float4*)src;
    float s = v.x + v.y + v.z + v.w;
    s += __shfl_xor(s, 1); s += __shfl_xor(s, 2); s += __shfl_xor(s, 4);
    s += __shfl_xor(s, 8); s += __shfl_xor(s, 16);
    float mu = s * (1.0f / 128.0f);
    float d0 = v.x - mu, d1 = v.y - mu, d2 = v.z - mu, d3 = v.w - mu;
    float q = d0 * d0 + d1 * d1 + d2 * d2 + d3 * d3;
    q += __shfl_xor(q, 1); q += __shfl_xor(q, 2); q += __shfl_xor(q, 4);
    q += __shfl_xor(q, 8); q += __shfl_xor(q, 16);
    float rs = rsqrtf(q * (1.0f / 128.0f) + 1e-5f);
    float4 gg = *(const float4*)(g2 + lh * 4);
    float4 bb = *(const float4*)(b2 + lh * 4);
    uint2 pk;
    pk.x = cvtpk(d0 * rs * gg.x + bb.x, d1 * rs * gg.y + bb.y);
    pk.y = cvtpk(d2 * rs * gg.z + bb.z, d3 * rs * gg.w + bb.w);
    *(uint2*)(Xl + rloc * 256 + ((lh * 8) ^ SWZ(rloc))) = pk;
  }
  __syncthreads();

  f32x4 acc2[4] = {fz, fz, fz, fz};
  #pragma unroll 1
  for (int q = 0; q < 4; q++) {
    // --- fc1 quarter: wave wv -> hidden cols [q*128 + wv*16, +16), all 64 rows
    f32x4 acc[4] = {fz, fz, fz, fz};
    #pragma unroll
    for (int ks = 0; ks < 4; ks++) {
      short8 wb = ld8(w1 + (size_t)(q * 128 + wv * 16 + lo) * 128 + ks * 32 + hi * 8);
      #pragma unroll
      for (int mt = 0; mt < 4; mt++) {
        int row = mt * 16 + lo;
        short8 a = *(const short8*)(Xl + row * 256 + ((ks * 64 + hi * 16) ^ SWZ(row)));
        acc[mt] = __builtin_amdgcn_mfma_f32_16x16x32_bf16(a, wb, acc[mt], 0, 0, 0);
      }
    }
    if (q) __syncthreads();   // previous quarter's fc2 reads must finish before Hq overwrite
    float bv = bias1[q * 128 + wv * 16 + lo];
    #pragma unroll
    for (int mt = 0; mt < 4; mt++) {
      #pragma unroll
      for (int r = 0; r < 4; r++) {
        int row = mt * 16 + 4 * hi + r;
        float ge = gelu_f(acc[mt][r] + bv);
        *(unsigned short*)(Hq + row * 256 + ((2 * (wv * 16 + lo)) ^ SWZ(row))) = f2bf(ge);
      }
    }
    __syncthreads();
    // --- fc2 partial: wave wv -> out cols [wv*16, +16), k-quarter [q*128, +128)
    #pragma unroll
    for (int ks = 0; ks < 4; ks++) {
      short8 wb = ld8(w2 + (size_t)(wv * 16 + lo) * 512 + q * 128 + ks * 32 + hi * 8);
      #pragma unroll
      for (int mt = 0; mt < 4; mt++) {
        int row = mt * 16 + lo;
        short8 a = *(const short8*)(Hq + row * 256 + ((ks * 64 + hi * 16) ^ SWZ(row)));
        acc2[mt] = __builtin_amdgcn_mfma_f32_16x16x32_bf16(a, wb, acc2[mt], 0, 0, 0);
      }
    }
  }

  // --- epilogue: bias + residual, in-place on y
  int c = wv * 16 + lo;
  float bv2 = bias2[c];
  #pragma unroll
  for (int mt = 0; mt < 4; mt++) {
    #pragma unroll
    for (int r = 0; r < 4; r++) {
      size_t idx = (size_t)(m0 + mt * 16 + 4 * hi + r) * 128 + c;
      y[idx] = acc2[mt][r] + bv2 + y[idx];
    }
  }
}

// ---------------------------------------------------------------- launch
extern "C" void kernel_launch(void* const* d_in, const int* in_sizes, int n_in,
                              void* d_out, int out_size, void* d_ws, size_t ws_size,
                              hipStream_t stream) {
  const float* x     = (const float*)d_in[0];
  const float* ln1g  = (const float*)d_in[1];
  const float* ln1b  = (const float*)d_in[2];
  const float* qkvw  = (const float*)d_in[3];
  const float* qkvb  = (const float*)d_in[4];
  const float* rpb   = (const float*)d_in[5];
  const float* projw = (const float*)d_in[6];
  const float* projb = (const float*)d_in[7];
  const float* ln2g  = (const float*)d_in[8];
  const float* ln2b  = (const float*)d_in[9];
  const float* fc1w  = (const float*)d_in[10];
  const float* fc1b  = (const float*)d_in[11];
  const float* fc2w  = (const float*)d_in[12];
  const float* fc2b  = (const float*)d_in[13];
  float* out = (float*)d_out;
  char* ws = (char*)d_ws;

  // ws layout: bf16 weights [0, 384K) | addtab @512K (2.4MB). Total < 3MB.
  unsigned short* wbuf = (unsigned short*)ws;
  unsigned short* wq = wbuf;                       // 384x128
  unsigned short* wp = wbuf + 49152;               // 128x128
  unsigned short* w1 = wbuf + 65536;               // 512x128
  unsigned short* w2 = wbuf + 131072;              // 128x512
  float* addtab = (float*)(ws + (512u << 10));

  k_cvt<<<768, 256, 0, stream>>>(qkvw, projw, fc1w, fc2w, wbuf);
  k_addtab<<<2401, 256, 0, stream>>>(rpb, addtab);
  k_attn<<<4096, 256, 0, stream>>>(x, ln1g, ln1b, wq, qkvb, wp, projb, addtab, out);
  k_mlp<<<3136, 512, 0, stream>>>(out, ln2g, ln2b, w1, fc1b, w2, fc2b);
}

// Round 6
// 555.458 us; speedup vs baseline: 1.1016x; 1.1016x over previous
//
#include <hip/hip_runtime.h>

#define SCALEF 0.17677669529663687f                 // 32^-0.5
#define LOG2E 1.4426950408889634f
#define SCALE2 (0.17677669529663687f * 1.4426950408889634f)
#define SWZ(r) ((((r) & 3) << 6) | (((r) & 12) << 2))   // bf16 rows (256B): bits 4-7, b128-safe
#define SWZF(r) ((((r) & 1) << 6) | (((r) & 6) << 3))   // fp32 rows (512B): bits 4-6, b128-safe

typedef __attribute__((ext_vector_type(8))) short short8;   // 8 bf16
typedef __attribute__((ext_vector_type(4))) float f32x4;
typedef __attribute__((ext_vector_type(4))) unsigned int u32x4;

__device__ __forceinline__ unsigned short f2bf(float f) {
  unsigned u = __builtin_bit_cast(unsigned, f);
  u = (u + 0x7FFFu + ((u >> 16) & 1u)) >> 16;
  return (unsigned short)u;
}
__device__ __forceinline__ short8 ld8(const unsigned short* p) { return *(const short8*)p; }
__device__ __forceinline__ unsigned cvtpk(float a, float b) {
  unsigned d;
  asm("v_cvt_pk_bf16_f32 %0, %1, %2" : "=v"(d) : "v"(a), "v"(b));
  return d;
}

// Build an MFMA A/B-frag (lane lo -> row, k = hi*8+e) from two 16x16 C-tiles
// whose ROWS are the k-dimension (t0: k 0..15, t1: k 16..31).
__device__ __forceinline__ short8 xform(f32x4 t0, f32x4 t1, int lo, int hi) {
  unsigned A01 = cvtpk(t0[0], t0[1]), A23 = cvtpk(t0[2], t0[3]);
  unsigned B01 = cvtpk(t1[0], t1[1]), B23 = cvtpk(t1[2], t1[3]);
  int s0 = ((2 * hi) & 3) * 16 + lo;
  int s1 = ((2 * hi + 1) & 3) * 16 + lo;
  bool up = hi >= 2;
  unsigned a, b;
  a = __shfl(A01, s0); b = __shfl(B01, s0); unsigned dw0 = up ? b : a;
  a = __shfl(A23, s0); b = __shfl(B23, s0); unsigned dw1 = up ? b : a;
  a = __shfl(A01, s1); b = __shfl(B01, s1); unsigned dw2 = up ? b : a;
  a = __shfl(A23, s1); b = __shfl(B23, s1); unsigned dw3 = up ? b : a;
  u32x4 v = {dw0, dw1, dw2, dw3};
  return __builtin_bit_cast(short8, v);
}

// gelu(x) = x * sigmoid(1.5957691*(x+0.044715x^3)), exp2 domain.
__device__ __forceinline__ float gelu_f(float x) {
  float x2 = x * x;
  float t = __builtin_fmaf(-0.10294824f, x2, -2.30220823f);
  float e = __builtin_amdgcn_exp2f(t * x);
  return x * __builtin_amdgcn_rcpf(e + 1.0f);
}

// ---------------------------------------------------------------- K0a: weights fp32 -> bf16
__global__ __launch_bounds__(256) void k_cvt(const float* qkvw, const float* projw,
                                             const float* fc1w, const float* fc2w,
                                             unsigned short* wbuf) {
  int i = blockIdx.x * 256 + threadIdx.x;
  float v;
  if (i < 49152) v = qkvw[i];
  else if (i < 65536) v = projw[i - 49152];
  else if (i < 131072) v = fc1w[i - 65536];
  else v = fc2w[i - 131072];
  wbuf[i] = f2bf(v);
}

// ---------------------------------------------------------------- K0b: bias+mask table, TRANSPOSED [w][h][j][i], pre-scaled by log2e
__device__ __forceinline__ int regio(int r) { return r < 49 ? 0 : (r < 53 ? 1 : 2); }

__global__ __launch_bounds__(256) void k_addtab(const float* rpb, float* at) {
  int idx = blockIdx.x * 256 + threadIdx.x;      // 64*4*49*49 = 614656 threads
  int i = idx % 49;                               // query token
  int tmp = idx / 49;
  int j = tmp % 49; tmp /= 49;                    // key token
  int h = tmp & 3;
  int w = tmp >> 2;
  int ih = i / 7, iw = i % 7, jh = j / 7, jw = j % 7;
  int rpi = (ih - jh + 6) * 13 + (iw - jw + 6);
  float bias = rpb[rpi * 4 + h];
  int wr = w >> 3, wc = w & 7;
  int idi = regio(wr * 7 + ih) * 3 + regio(wc * 7 + iw);
  int idj = regio(wr * 7 + jh) * 3 + regio(wc * 7 + jw);
  at[idx] = (bias + ((idi != idj) ? -100.0f : 0.0f)) * LOG2E;
}

// ---------------------------------------------------------------- K1: fused LN1+QKV+attn+proj+residual
// 1 block/window, 1 wave/head. LDS 25 KB. No launch_bounds min (avoid VGPR cap/spill).
__global__ __launch_bounds__(256) void k_attn(const float* __restrict__ x,
                                              const float* __restrict__ g1,
                                              const float* __restrict__ b1,
                                              const unsigned short* __restrict__ wq,
                                              const float* __restrict__ qb,
                                              const unsigned short* __restrict__ wp,
                                              const float* __restrict__ pb,
                                              const float* __restrict__ addtab,
                                              float* __restrict__ y) {
  __shared__ __align__(16) char L[25088];   // phases 0-4: bf16 X/attnout (12.25KB); phase 6: fp32 proj-out (25KB)
  const int tid = threadIdx.x;
  const int wv = tid >> 6, l = tid & 63, lo = l & 15, hi = l >> 4;
  const int lh = l & 31, half = l >> 5;
  const int g = blockIdx.x, bimg = g >> 6, w_in = g & 63;
  const int wr = w_in >> 3, wc = w_in & 7;
  const int h = wv;
  const f32x4 fz = {0.f, 0.f, 0.f, 0.f};

  // ---- Phase 0: LN1 + roll(-3,-3) gather -> X (bf16, swizzled). 2 rows/iter (half-wave float4).
  #pragma unroll 1
  for (int ii = 0; ii < 7; ii++) {
    int r = ii * 8 + wv * 2 + half;
    if (r < 49) {
      int ihh = r / 7, iww = r - ihh * 7;
      int oh = wr * 7 + ihh + 3; if (oh >= 56) oh -= 56;
      int ow = wc * 7 + iww + 3; if (ow >= 56) ow -= 56;
      const float* src = x + ((size_t)bimg * 3136 + oh * 56 + ow) * 128 + lh * 4;
      float4 v = *(const float4*)src;
      float s = v.x + v.y + v.z + v.w;
      s += __shfl_xor(s, 1); s += __shfl_xor(s, 2); s += __shfl_xor(s, 4);
      s += __shfl_xor(s, 8); s += __shfl_xor(s, 16);
      float mu = s * (1.0f / 128.0f);
      float d0 = v.x - mu, d1 = v.y - mu, d2 = v.z - mu, d3 = v.w - mu;
      float q = d0 * d0 + d1 * d1 + d2 * d2 + d3 * d3;
      q += __shfl_xor(q, 1); q += __shfl_xor(q, 2); q += __shfl_xor(q, 4);
      q += __shfl_xor(q, 8); q += __shfl_xor(q, 16);
      float rs = rsqrtf(q * (1.0f / 128.0f) + 1e-5f);
      float4 gg = *(const float4*)(g1 + lh * 4);
      float4 bb = *(const float4*)(b1 + lh * 4);
      uint2 pk;
      pk.x = cvtpk(d0 * rs * gg.x + bb.x, d1 * rs * gg.y + bb.y);
      pk.y = cvtpk(d2 * rs * gg.z + bb.z, d3 * rs * gg.w + bb.w);
      *(uint2*)(L + r * 256 + ((lh * 8) ^ SWZ(r))) = pk;
    }
  }
  __syncthreads();

  // ---- Phase 1: Q^T and K^T GEMMs (merged, share X-fragment reads) -> in-reg frags
  short8 qbf[4], kaf[4];
  {
    f32x4 cq[2][4], ck[2][4];
    #pragma unroll
    for (int a = 0; a < 2; a++)
      #pragma unroll
      for (int b = 0; b < 4; b++) { cq[a][b] = fz; ck[a][b] = fz; }
    #pragma unroll
    for (int ks = 0; ks < 4; ks++) {
      short8 wq0 = ld8(wq + (size_t)(h * 32 + lo) * 128 + ks * 32 + hi * 8);
      short8 wq1 = ld8(wq + (size_t)(h * 32 + 16 + lo) * 128 + ks * 32 + hi * 8);
      short8 wk0 = ld8(wq + (size_t)(128 + h * 32 + lo) * 128 + ks * 32 + hi * 8);
      short8 wk1 = ld8(wq + (size_t)(128 + h * 32 + 16 + lo) * 128 + ks * 32 + hi * 8);
      #pragma unroll
      for (int nt = 0; nt < 4; nt++) {
        int row = nt * 16 + lo; if (row > 48) row = 48;
        short8 xbv = *(const short8*)(L + row * 256 + ((ks * 64 + hi * 16) ^ SWZ(row)));
        cq[0][nt] = __builtin_amdgcn_mfma_f32_16x16x32_bf16(wq0, xbv, cq[0][nt], 0, 0, 0);
        cq[1][nt] = __builtin_amdgcn_mfma_f32_16x16x32_bf16(wq1, xbv, cq[1][nt], 0, 0, 0);
        ck[0][nt] = __builtin_amdgcn_mfma_f32_16x16x32_bf16(wk0, xbv, ck[0][nt], 0, 0, 0);
        ck[1][nt] = __builtin_amdgcn_mfma_f32_16x16x32_bf16(wk1, xbv, ck[1][nt], 0, 0, 0);
      }
    }
    float4 qb0 = *(const float4*)(qb + h * 32 + 4 * hi);
    float4 qb1 = *(const float4*)(qb + h * 32 + 16 + 4 * hi);
    float4 kb0 = *(const float4*)(qb + 128 + h * 32 + 4 * hi);
    float4 kb1 = *(const float4*)(qb + 128 + h * 32 + 16 + 4 * hi);
    #pragma unroll
    for (int nt = 0; nt < 4; nt++) {
      f32x4 t0 = cq[0][nt], t1 = cq[1][nt];
      t0[0] += qb0.x; t0[1] += qb0.y; t0[2] += qb0.z; t0[3] += qb0.w;
      t1[0] += qb1.x; t1[1] += qb1.y; t1[2] += qb1.z; t1[3] += qb1.w;
      qbf[nt] = xform(t0, t1, lo, hi);
      t0 = ck[0][nt]; t1 = ck[1][nt];
      t0[0] += kb0.x; t0[1] += kb0.y; t0[2] += kb0.z; t0[3] += kb0.w;
      t1[0] += kb1.x; t1[1] += kb1.y; t1[2] += kb1.z; t1[3] += kb1.w;
      kaf[nt] = xform(t0, t1, lo, hi);
    }
  }

  // ---- Phase 2: V GEMM (untransposed), eager pair-xform -> in-reg B-frags vf[dtile][ks]
  short8 vf[2][2];
  {
    #pragma unroll
    for (int nt = 0; nt < 2; nt++) {
      float vb = qb[256 + h * 32 + nt * 16 + lo];
      #pragma unroll
      for (int p = 0; p < 2; p++) {
        f32x4 c0 = fz, c1 = fz;
        #pragma unroll
        for (int ks = 0; ks < 4; ks++) {
          short8 wb = ld8(wq + (size_t)(256 + h * 32 + nt * 16 + lo) * 128 + ks * 32 + hi * 8);
          int r0 = p * 32 + lo; if (r0 > 48) r0 = 48;
          int r1 = p * 32 + 16 + lo; if (r1 > 48) r1 = 48;
          short8 xa0 = *(const short8*)(L + r0 * 256 + ((ks * 64 + hi * 16) ^ SWZ(r0)));
          short8 xa1 = *(const short8*)(L + r1 * 256 + ((ks * 64 + hi * 16) ^ SWZ(r1)));
          c0 = __builtin_amdgcn_mfma_f32_16x16x32_bf16(xa0, wb, c0, 0, 0, 0);
          c1 = __builtin_amdgcn_mfma_f32_16x16x32_bf16(xa1, wb, c1, 0, 0, 0);
        }
        c0[0] += vb; c0[1] += vb; c0[2] += vb; c0[3] += vb;
        c1[0] += vb; c1[1] += vb; c1[2] += vb; c1[3] += vb;
        vf[nt][p] = xform(c0, c1, lo, hi);
      }
    }
  }
  __syncthreads();   // all X reads done block-wide; attnout may overwrite X region

  // ---- Phase 3+4 fused per i-tile: QK^T -> softmax -> PV -> stage o (keeps st live = 16 VGPRs)
  const float* at = addtab + ((size_t)w_in * 4 + h) * 2401;
  #pragma unroll
  for (int it = 0; it < 4; it++) {
    f32x4 st[4];
    #pragma unroll
    for (int jt = 0; jt < 4; jt++)
      st[jt] = __builtin_amdgcn_mfma_f32_16x16x32_bf16(kaf[jt], qbf[it], fz, 0, 0, 0);

    int i = it * 16 + lo;
    int ic = i > 48 ? 48 : i;
    #pragma unroll
    for (int jt = 0; jt < 4; jt++) {
      #pragma unroll
      for (int r = 0; r < 4; r++) {
        int jj = jt * 16 + 4 * hi + r;
        int jc = jj > 48 ? 48 : jj;
        float sv = st[jt][r] * SCALE2 + at[jc * 49 + ic];
        st[jt][r] = (jj < 49) ? sv : -1e30f;
      }
    }
    float mx = -1e30f;
    #pragma unroll
    for (int jt = 0; jt < 4; jt++)
      mx = fmaxf(mx, fmaxf(fmaxf(st[jt][0], st[jt][1]), fmaxf(st[jt][2], st[jt][3])));
    mx = fmaxf(mx, __shfl_xor(mx, 16));
    mx = fmaxf(mx, __shfl_xor(mx, 32));
    float sum = 0.0f;
    #pragma unroll
    for (int jt = 0; jt < 4; jt++)
      #pragma unroll
      for (int r = 0; r < 4; r++) {
        st[jt][r] = __builtin_amdgcn_exp2f(st[jt][r] - mx);
        sum += st[jt][r];
      }
    sum += __shfl_xor(sum, 16);
    sum += __shfl_xor(sum, 32);
    float rinv = 1.0f / sum;
    #pragma unroll
    for (int jt = 0; jt < 4; jt++)
      #pragma unroll
      for (int r = 0; r < 4; r++)
        st[jt][r] *= rinv;

    short8 pf0 = xform(st[0], st[1], lo, hi);
    short8 pf1 = xform(st[2], st[3], lo, hi);
    f32x4 o0 = fz, o1 = fz;
    o0 = __builtin_amdgcn_mfma_f32_16x16x32_bf16(pf0, vf[0][0], o0, 0, 0, 0);
    o0 = __builtin_amdgcn_mfma_f32_16x16x32_bf16(pf1, vf[0][1], o0, 0, 0, 0);
    o1 = __builtin_amdgcn_mfma_f32_16x16x32_bf16(pf0, vf[1][0], o1, 0, 0, 0);
    o1 = __builtin_amdgcn_mfma_f32_16x16x32_bf16(pf1, vf[1][1], o1, 0, 0, 0);
    #pragma unroll
    for (int r = 0; r < 4; r++) {
      int irow = it * 16 + 4 * hi + r;
      if (irow < 49) {
        int c0 = h * 32 + lo, c1 = h * 32 + 16 + lo;
        *(unsigned short*)(L + irow * 256 + ((2 * c0) ^ SWZ(irow))) = f2bf(o0[r]);
        *(unsigned short*)(L + irow * 256 + ((2 * c1) ^ SWZ(irow))) = f2bf(o1[r]);
      }
    }
  }
  __syncthreads();

  // ---- Phase 5: proj GEMM; wave wv -> cols [wv*32, +32)
  f32x4 pacc[4][2];
  #pragma unroll
  for (int a = 0; a < 4; a++) { pacc[a][0] = fz; pacc[a][1] = fz; }
  #pragma unroll
  for (int ks = 0; ks < 4; ks++) {
    short8 wb0 = ld8(wp + (size_t)(wv * 32 + lo) * 128 + ks * 32 + hi * 8);
    short8 wb1 = ld8(wp + (size_t)(wv * 32 + 16 + lo) * 128 + ks * 32 + hi * 8);
    #pragma unroll
    for (int mt = 0; mt < 4; mt++) {
      int tok = mt * 16 + lo; if (tok > 48) tok = 48;
      short8 a = *(const short8*)(L + tok * 256 + ((ks * 64 + hi * 16) ^ SWZ(tok)));
      pacc[mt][0] = __builtin_amdgcn_mfma_f32_16x16x32_bf16(a, wb0, pacc[mt][0], 0, 0, 0);
      pacc[mt][1] = __builtin_amdgcn_mfma_f32_16x16x32_bf16(a, wb1, pacc[mt][1], 0, 0, 0);
    }
  }
  __syncthreads();   // all attnout reads done; safe to overwrite with fp32 proj-out

  // ---- stage proj-out fp32 into L (49 x 512B, SWZF-swizzled)
  #pragma unroll
  for (int mt = 0; mt < 4; mt++) {
    #pragma unroll
    for (int r = 0; r < 4; r++) {
      int tok = mt * 16 + 4 * hi + r;
      if (tok < 49) {
        int c0 = wv * 32 + lo, c1 = wv * 32 + 16 + lo;
        *(float*)(L + tok * 512 + ((4 * c0) ^ SWZF(tok))) = pacc[mt][0][r];
        *(float*)(L + tok * 512 + ((4 * c1) ^ SWZF(tok))) = pacc[mt][1][r];
      }
    }
  }
  __syncthreads();

  // ---- Phase 6: coalesced epilogue: y = proj_out + pb + x (roll(+3), window-reverse)
  float4 pb4 = *(const float4*)(pb + lh * 4);
  #pragma unroll 1
  for (int ii = 0; ii < 7; ii++) {
    int t = ii * 8 + wv * 2 + half;
    if (t < 49) {
      int ihh = t / 7, iww = t - ihh * 7;
      int oh = wr * 7 + ihh + 3; if (oh >= 56) oh -= 56;
      int ow = wc * 7 + iww + 3; if (ow >= 56) ow -= 56;
      size_t yrow = (size_t)bimg * 3136 + oh * 56 + ow;
      float4 pv = *(const float4*)(L + t * 512 + ((16 * lh) ^ SWZF(t)));
      float4 xv = *(const float4*)(x + yrow * 128 + lh * 4);
      float4 out;
      out.x = pv.x + pb4.x + xv.x;
      out.y = pv.y + pb4.y + xv.y;
      out.z = pv.z + pb4.z + xv.z;
      out.w = pv.w + pb4.w + xv.w;
      *(float4*)(y + yrow * 128 + lh * 4) = out;
    }
  }
}

// ---------------------------------------------------------------- K2: fused LN2+fc1+GELU+fc2+residual, double-buffered quarter-H
// 512 threads (8 waves), 64 rows/block, LDS 48 KB -> 3 blocks/CU (24 waves).
__global__ __launch_bounds__(512, 8) void k_mlp(float* __restrict__ y,
                                                const float* __restrict__ g2, const float* __restrict__ b2,
                                                const unsigned short* __restrict__ w1, const float* __restrict__ bias1,
                                                const unsigned short* __restrict__ w2, const float* __restrict__ bias2) {
  __shared__ __align__(16) char Xl[16384];      // 64 x 256B, swizzled
  __shared__ __align__(16) char Hq[2][16384];   // double-buffered 128-col quarter of H
  const int m0 = blockIdx.x * 64;
  const int tid = threadIdx.x;
  const int wv = tid >> 6, l = tid & 63, lo = l & 15, hi = l >> 4;
  const int lh = l & 31, half = l >> 5;
  const f32x4 fz = {0.f, 0.f, 0.f, 0.f};

  // --- LN2: 4 iters x 16 rows (8 waves x 2 rows, half-wave float4)
  #pragma unroll 1
  for (int it = 0; it < 4; it++) {
    int rloc = it * 16 + wv * 2 + half;
    const float* src = y + (size_t)(m0 + rloc) * 128 + lh * 4;
    float4 v = *(const float4*)src;
    float s = v.x + v.y + v.z + v.w;
    s += __shfl_xor(s, 1); s += __shfl_xor(s, 2); s += __shfl_xor(s, 4);
    s += __shfl_xor(s, 8); s += __shfl_xor(s, 16);
    float mu = s * (1.0f / 128.0f);
    float d0 = v.x - mu, d1 = v.y - mu, d2 = v.z - mu, d3 = v.w - mu;
    float q = d0 * d0 + d1 * d1 + d2 * d2 + d3 * d3;
    q += __shfl_xor(q, 1); q += __shfl_xor(q, 2); q += __shfl_xor(q, 4);
    q += __shfl_xor(q, 8); q += __shfl_xor(q, 16);
    float rs = rsqrtf(q * (1.0f / 128.0f) + 1e-5f);
    float4 gg = *(const float4*)(g2 + lh * 4);
    float4 bb = *(const float4*)(b2 + lh * 4);
    uint2 pk;
    pk.x = cvtpk(d0 * rs * gg.x + bb.x, d1 * rs * gg.y + bb.y);
    pk.y = cvtpk(d2 * rs * gg.z + bb.z, d3 * rs * gg.w + bb.w);
    *(uint2*)(Xl + rloc * 256 + ((lh * 8) ^ SWZ(rloc))) = pk;
  }
  __syncthreads();

  f32x4 acc2[4] = {fz, fz, fz, fz};
  #pragma unroll 1
  for (int q = 0; q < 4; q++) {
    char* Hb = Hq[q & 1];
    // --- fc1 quarter: wave wv -> hidden cols [q*128 + wv*16, +16), all 64 rows
    f32x4 acc[4] = {fz, fz, fz, fz};
    #pragma unroll
    for (int ks = 0; ks < 4; ks++) {
      short8 wb = ld8(w1 + (size_t)(q * 128 + wv * 16 + lo) * 128 + ks * 32 + hi * 8);
      #pragma unroll
      for (int mt = 0; mt < 4; mt++) {
        int row = mt * 16 + lo;
        short8 a = *(const short8*)(Xl + row * 256 + ((ks * 64 + hi * 16) ^ SWZ(row)));
        acc[mt] = __builtin_amdgcn_mfma_f32_16x16x32_bf16(a, wb, acc[mt], 0, 0, 0);
      }
    }
    float bv = bias1[q * 128 + wv * 16 + lo];
    #pragma unroll
    for (int mt = 0; mt < 4; mt++) {
      #pragma unroll
      for (int r = 0; r < 4; r++) {
        int row = mt * 16 + 4 * hi + r;
        float ge = gelu_f(acc[mt][r] + bv);
        *(unsigned short*)(Hb + row * 256 + ((2 * (wv * 16 + lo)) ^ SWZ(row))) = f2bf(ge);
      }
    }
    __syncthreads();
    // --- fc2 partial: wave wv -> out cols [wv*16, +16), k-quarter [q*128, +128)
    #pragma unroll
    for (int ks = 0; ks < 4; ks++) {
      short8 wb = ld8(w2 + (size_t)(wv * 16 + lo) * 512 + q * 128 + ks * 32 + hi * 8);
      #pragma unroll
      for (int mt = 0; mt < 4; mt++) {
        int row = mt * 16 + lo;
        short8 a = *(const short8*)(Hb + row * 256 + ((ks * 64 + hi * 16) ^ SWZ(row)));
        acc2[mt] = __builtin_amdgcn_mfma_f32_16x16x32_bf16(a, wb, acc2[mt], 0, 0, 0);
      }
    }
  }

  // --- epilogue: bias + residual, in-place on y
  int c = wv * 16 + lo;
  float bv2 = bias2[c];
  #pragma unroll
  for (int mt = 0; mt < 4; mt++) {
    #pragma unroll
    for (int r = 0; r < 4; r++) {
      size_t idx = (size_t)(m0 + mt * 16 + 4 * hi + r) * 128 + c;
      y[idx] = acc2[mt][r] + bv2 + y[idx];
    }
  }
}

// ---------------------------------------------------------------- launch
extern "C" void kernel_launch(void* const* d_in, const int* in_sizes, int n_in,
                              void* d_out, int out_size, void* d_ws, size_t ws_size,
                              hipStream_t stream) {
  const float* x     = (const float*)d_in[0];
  const float* ln1g  = (const float*)d_in[1];
  const float* ln1b  = (const float*)d_in[2];
  const float* qkvw  = (const float*)d_in[3];
  const float* qkvb  = (const float*)d_in[4];
  const float* rpb   = (const float*)d_in[5];
  const float* projw = (const float*)d_in[6];
  const float* projb = (const float*)d_in[7];
  const float* ln2g  = (const float*)d_in[8];
  const float* ln2b  = (const float*)d_in[9];
  const float* fc1w  = (const float*)d_in[10];
  const float* fc1b  = (const float*)d_in[11];
  const float* fc2w  = (const float*)d_in[12];
  const float* fc2b  = (const float*)d_in[13];
  float* out = (float*)d_out;
  char* ws = (char*)d_ws;

  // ws layout: bf16 weights [0, 384K) | addtab @512K (2.4MB). Total < 3MB.
  unsigned short* wbuf = (unsigned short*)ws;
  unsigned short* wq = wbuf;                       // 384x128
  unsigned short* wp = wbuf + 49152;               // 128x128
  unsigned short* w1 = wbuf + 65536;               // 512x128
  unsigned short* w2 = wbuf + 131072;              // 128x512
  float* addtab = (float*)(ws + (512u << 10));

  k_cvt<<<768, 256, 0, stream>>>(qkvw, projw, fc1w, fc2w, wbuf);
  k_addtab<<<2401, 256, 0, stream>>>(rpb, addtab);
  k_attn<<<4096, 256, 0, stream>>>(x, ln1g, ln1b, wq, qkvb, wp, projb, addtab, out);
  k_mlp<<<3136, 512, 0, stream>>>(out, ln2g, ln2b, w1, fc1b, w2, fc2b);
}